// Round 4
// baseline (336.072 us; speedup 1.0000x reference)
//
#include <hip/hip_runtime.h>
#include <hip/hip_bf16.h>

typedef __attribute__((ext_vector_type(8))) short bf16x8;
typedef __attribute__((ext_vector_type(4))) float f32x4;

#define HWSZ 4096
#define NPIX 16384

__device__ inline float b2f(short s) {
  return __uint_as_float(((unsigned)(unsigned short)s) << 16);
}
__device__ inline short f2b(float f) {
  __hip_bfloat16 h = __float2bfloat16(f);
  return *(short*)&h;
}
__device__ inline void gl16(const short* g, short* l) {
  __builtin_amdgcn_global_load_lds(
      (const __attribute__((address_space(1))) unsigned int*)g,
      (__attribute__((address_space(3))) unsigned int*)l, 16, 0, 0);
}

// ---------------- weight fp32 -> bf16 conversion ----------------
// wbf per bi (elems): qw 0, kw 65536, vw 131072, pw 196608, fc1w 262144, fc2w 524288; total 786432
__global__ __launch_bounds__(256) void convert_k(
    const float* __restrict__ qw, const float* __restrict__ kw,
    const float* __restrict__ vw, const float* __restrict__ pw,
    const float* __restrict__ f1, const float* __restrict__ f2,
    __hip_bfloat16* __restrict__ out)
{
  int idx = blockIdx.x * 256 + threadIdx.x;
  if (idx >= 2 * 786432) return;
  int bi = idx / 786432;
  int r  = idx - bi * 786432;
  float v;
  if      (r <  65536) v = qw[bi*65536 + r];
  else if (r < 131072) v = kw[bi*65536 + r - 65536];
  else if (r < 196608) v = vw[bi*65536 + r - 131072];
  else if (r < 262144) v = pw[bi*65536 + r - 196608];
  else if (r < 524288) v = f1[bi*262144 + r - 262144];
  else                 v = f2[bi*262144 + r - 524288];
  out[idx] = __float2bfloat16(v);
}

// ---------------- fused prep: both LN1 variants + raw diff, BCHW -> (pix, ch) ----------------
__global__ __launch_bounds__(256) void prep2_k(
    const float* __restrict__ x,     // (2,4,256,64,64)
    const float* __restrict__ nw, const float* __restrict__ nb,
    __hip_bfloat16* __restrict__ ln1a,   // LN(av*vi+ai*ir)
    __hip_bfloat16* __restrict__ ln1b,   // LN(bv*vi+bb*ir)
    float* __restrict__ diff,            // av*vi+ai*ir (raw)
    float av, float ai, float bv, float bb)
{
  __shared__ float t1[16][257], t2[16][257];
  __shared__ float red[4][16][16];
  __shared__ float mu1[16], rs1[16], mu2[16], rs2[16];
  int t = threadIdx.x;
  int pix0 = blockIdx.x * 16;
  int b = pix0 >> 12, hw0 = pix0 & 4095;
  const float* vi = x + (size_t)b * 256 * HWSZ;
  const float* ir = x + (size_t)(4 + b) * 256 * HWSZ;

  for (int it = 0; it < 16; ++it) {
    int idx = it * 256 + t;
    int p = idx & 15, c = idx >> 4;
    size_t off = (size_t)c * HWSZ + hw0 + p;
    float a = vi[off], bb2 = ir[off];
    t1[p][c] = av * a + ai * bb2;
    t2[p][c] = bv * a + bb * bb2;
  }
  __syncthreads();
  {
    int p = t & 15, q = t >> 4;
    float s1 = 0, ss1 = 0, s2 = 0, ss2 = 0;
    for (int i = 0; i < 16; ++i) {
      float v = t1[p][q*16 + i]; s1 += v; ss1 += v*v;
      float u = t2[p][q*16 + i]; s2 += u; ss2 += u*u;
    }
    red[0][p][q] = s1; red[1][p][q] = ss1; red[2][p][q] = s2; red[3][p][q] = ss2;
  }
  __syncthreads();
  if (t < 32) {
    int p = t & 15, which = t >> 4;
    float s = 0, ss = 0;
    for (int q = 0; q < 16; ++q) { s += red[which*2][p][q]; ss += red[which*2+1][p][q]; }
    float mu = s * (1.f/256.f);
    float var = ss * (1.f/256.f) - mu*mu;
    float rs = rsqrtf(var + 1e-5f);
    if (which == 0) { mu1[p] = mu; rs1[p] = rs; }
    else            { mu2[p] = mu; rs2[p] = rs; }
  }
  __syncthreads();
  for (int it = 0; it < 16; ++it) {
    float v1 = t1[it][t], v2 = t2[it][t];
    size_t o = (size_t)(pix0 + it) * 256 + t;
    ln1a[o] = __float2bfloat16((v1 - mu1[it]) * rs1[it] * nw[t] + nb[t]);
    ln1b[o] = __float2bfloat16((v2 - mu2[it]) * rs2[it] * nw[t] + nb[t]);
    diff[o] = v1;
  }
}

// ---------------- A-stationary MFMA GEMM: C[M x N] = A[M x K] * W[N x K]^T ----------------
// Block 128(M) x 64(N); 4 waves 2x2; wave tile 64x32 (4x2 frags of 16x16x32).
// A staged in LDS per 256-wide K-chunk (64 KB, one barrier pair per chunk) with chunk-XOR
// swizzle c^=(row&7) applied on SOURCE (global addr) and READ (ds addr). B (weights) read
// global->reg, hoisted before the barrier; L2-resident.
// EPI 0: bf16 out[row*ldc+col]
// EPI 1: fp32 out = acc + bias[col] + res[row*Nres+col]
// EPI 2: bf16 out = gelu(acc + bias[col])
// EPI 3: fp32 BCHW: out[(b*256+col)*4096 + hw] = acc + bias[col] + res[row*Nres+col], gpix=row+row_base
template<int EPI>
__global__ __launch_bounds__(256) void gemm3_k(
    const short* __restrict__ A, const short* __restrict__ W,
    void* __restrict__ outp, const float* __restrict__ bias,
    const float* __restrict__ res,
    int K, int ldc, int Nres, int row_base)
{
  __shared__ __align__(16) short As[128 * 256];   // 64 KB
  int tid = threadIdx.x;
  int l = tid & 63, wv = tid >> 6;
  int wm = wv >> 1, wn = wv & 1;
  int m0 = blockIdx.x * 128;
  int n0 = blockIdx.y * 64;
  int lr = l & 15, lq = l >> 4;

  f32x4 acc[4][2];
  #pragma unroll
  for (int mi = 0; mi < 4; ++mi)
    #pragma unroll
    for (int ni = 0; ni < 2; ++ni) acc[mi][ni] = (f32x4){0.f, 0.f, 0.f, 0.f};

  const short* pB = W + (size_t)(n0 + wn * 32 + lr) * K + lq * 8;

  for (int kb = 0; kb < K; kb += 256) {
    // hoisted B-fragment loads for this k-chunk (global, L2-broadcast)
    bf16x8 bfall[8][2];
    #pragma unroll
    for (int ks = 0; ks < 8; ++ks)
      #pragma unroll
      for (int ni = 0; ni < 2; ++ni)
        bfall[ks][ni] = *(const bf16x8*)(pB + (size_t)ni * 16 * K + kb + ks * 32);

    // stage A[m0..m0+128)[kb..kb+256) -> LDS, coalesced rows, source-side XOR swizzle
    #pragma unroll
    for (int i = 0; i < 16; ++i) {
      int idx = i * 256 + tid;
      int row = idx >> 5, c = idx & 31;
      const short* g = A + (size_t)(m0 + row) * K + kb + ((c ^ (row & 7)) << 3);
      gl16(g, As + idx * 8);
    }
    __syncthreads();

    #pragma unroll
    for (int ks = 0; ks < 8; ++ks) {
      int kc0 = ks * 4 + lq;
      bf16x8 af[4];
      #pragma unroll
      for (int mi = 0; mi < 4; ++mi) {
        int row = wm * 64 + mi * 16 + lr;
        int kc = kc0 ^ (row & 7);
        af[mi] = *(const bf16x8*)(As + row * 256 + kc * 8);
      }
      #pragma unroll
      for (int mi = 0; mi < 4; ++mi)
        #pragma unroll
        for (int ni = 0; ni < 2; ++ni)
          acc[mi][ni] = __builtin_amdgcn_mfma_f32_16x16x32_bf16(af[mi], bfall[ks][ni], acc[mi][ni], 0, 0, 0);
    }
    __syncthreads();
  }

  #pragma unroll
  for (int mi = 0; mi < 4; ++mi)
  #pragma unroll
  for (int ni = 0; ni < 2; ++ni) {
    #pragma unroll
    for (int r = 0; r < 4; ++r) {
      int row = m0 + wm * 64 + mi * 16 + lq * 4 + r;
      int col = n0 + wn * 32 + ni * 16 + lr;
      float v = acc[mi][ni][r];
      if (EPI == 0) {
        ((__hip_bfloat16*)outp)[(size_t)row * ldc + col] = __float2bfloat16(v);
      } else if (EPI == 1) {
        v += bias[col] + res[(size_t)row * Nres + col];
        ((float*)outp)[(size_t)row * ldc + col] = v;
      } else if (EPI == 2) {
        v += bias[col];
        v = 0.5f * v * (1.f + erff(v * 0.70710678118654752f));
        ((__hip_bfloat16*)outp)[(size_t)row * ldc + col] = __float2bfloat16(v);
      } else {
        v += bias[col] + res[(size_t)row * Nres + col];
        int gpix = row + row_base;
        int b = gpix >> 12, hw = gpix & 4095;
        ((float*)outp)[(size_t)(b * 256 + col) * HWSZ + hw] = v;
      }
    }
  }
}

// ---------------- dilated local attention: one thread per (pixel, head) ----------------
// Q: [16384][256]; KV: [16384][512] (K cols 0-255, V cols 256-511); out [16384][256]
__global__ __launch_bounds__(256) void attn2_k(
    const __hip_bfloat16* __restrict__ Q,
    const __hip_bfloat16* __restrict__ KV,
    __hip_bfloat16* __restrict__ out)
{
  int gid = blockIdx.x * 256 + threadIdx.x;
  int pix = gid >> 3, head = gid & 7;
  int dil = (head >> 1) + 1;
  int y = (pix >> 6) & 63, xc = pix & 63;
  int base = pix & ~4095;
  const short* q8 = (const short*)Q + (size_t)pix * 256 + head * 32;
  float qf[32];
  #pragma unroll
  for (int j = 0; j < 4; ++j) {
    bf16x8 v = *(const bf16x8*)(q8 + j * 8);
    #pragma unroll
    for (int e = 0; e < 8; ++e) qf[j*8 + e] = b2f(v[e]);
  }
  float lg[9];
  int npx[9];
  #pragma unroll
  for (int t = 0; t < 9; ++t) {
    int ny = y + (t / 3 - 1) * dil;
    int nx = xc + (t % 3 - 1) * dil;
    bool ok = ((unsigned)ny < 64u) && ((unsigned)nx < 64u);
    npx[t] = ok ? (base | (ny * 64 + nx)) : -1;
    float d = 0.f;
    if (ok) {
      const short* k8 = (const short*)KV + (size_t)npx[t] * 512 + head * 32;
      #pragma unroll
      for (int j = 0; j < 4; ++j) {
        bf16x8 v = *(const bf16x8*)(k8 + j * 8);
        #pragma unroll
        for (int e = 0; e < 8; ++e) d += qf[j*8 + e] * b2f(v[e]);
      }
    }
    lg[t] = d * 0.17677669529663687f;   // 32^-0.5
  }
  float m = lg[0];
  #pragma unroll
  for (int t = 1; t < 9; ++t) m = fmaxf(m, lg[t]);
  float w[9], den = 0.f;
  #pragma unroll
  for (int t = 0; t < 9; ++t) { w[t] = expf(lg[t] - m); den += w[t]; }
  float inv = 1.f / den;
  float acc[32];
  #pragma unroll
  for (int j = 0; j < 32; ++j) acc[j] = 0.f;
  #pragma unroll
  for (int t = 0; t < 9; ++t) {
    if (npx[t] >= 0) {
      const short* v8 = (const short*)KV + (size_t)npx[t] * 512 + 256 + head * 32;
      float wt = w[t];
      #pragma unroll
      for (int j = 0; j < 4; ++j) {
        bf16x8 v = *(const bf16x8*)(v8 + j * 8);
        #pragma unroll
        for (int e = 0; e < 8; ++e) acc[j*8 + e] += wt * b2f(v[e]);
      }
    }
  }
  short* op = (short*)out + (size_t)pix * 256 + head * 32;
  #pragma unroll
  for (int j = 0; j < 4; ++j) {
    bf16x8 o;
    #pragma unroll
    for (int e = 0; e < 8; ++e) o[e] = f2b(acc[j*8 + e] * inv);
    *(bf16x8*)(op + j * 8) = o;
  }
}

// ---------------- LN2: fp32 (pix,ch) -> bf16 (pix,ch) ----------------
__global__ __launch_bounds__(256) void ln2_k(
    const float* __restrict__ xm, const float* __restrict__ w2,
    const float* __restrict__ b2, __hip_bfloat16* __restrict__ h)
{
  int pix = blockIdx.x * 4 + (threadIdx.x >> 6);
  int l = threadIdx.x & 63;
  const float4 v = *(const float4*)(xm + (size_t)pix * 256 + l * 4);
  float s  = v.x + v.y + v.z + v.w;
  float ss = v.x*v.x + v.y*v.y + v.z*v.z + v.w*v.w;
  #pragma unroll
  for (int off = 32; off; off >>= 1) { s += __shfl_xor(s, off); ss += __shfl_xor(ss, off); }
  float mu = s * (1.f/256.f);
  float rstd = rsqrtf(ss * (1.f/256.f) - mu*mu + 1e-5f);
  float vv[4] = {v.x, v.y, v.z, v.w};
  #pragma unroll
  for (int j = 0; j < 4; ++j) {
    int c = l * 4 + j;
    h[(size_t)pix * 256 + c] = __float2bfloat16((vv[j] - mu) * rstd * w2[c] + b2[c]);
  }
}

extern "C" void kernel_launch(void* const* d_in, const int* in_sizes, int n_in,
                              void* d_out, int out_size, void* d_ws, size_t ws_size,
                              hipStream_t stream)
{
  const float* x   = (const float*)d_in[0];
  const float* n1w = (const float*)d_in[1];
  const float* n1b = (const float*)d_in[2];
  const float* qw  = (const float*)d_in[3];
  const float* kw  = (const float*)d_in[4];
  const float* vw  = (const float*)d_in[5];
  const float* pw  = (const float*)d_in[6];
  const float* pb  = (const float*)d_in[7];
  const float* n2w = (const float*)d_in[8];
  const float* n2b = (const float*)d_in[9];
  const float* f1w = (const float*)d_in[10];
  const float* f1b = (const float*)d_in[11];
  const float* f2w = (const float*)d_in[12];
  const float* f2b = (const float*)d_in[13];
  float* outp = (float*)d_out;
  char* ws = (char*)d_ws;

  const size_t MB = 1024 * 1024;
  // Workspace high-water 51 MB. Lifetimes per bi:
  //   [0,3)   wbf (whole session)
  //   [3,11)  ln1b -> attnb
  //   [11,27) diff fp32 -> h1h
  //   [27,35) qbuf --\
  //   [27,43)         xmid fp32 (after attn; overlaps dead qbuf + kv-low)
  //   [35,43) ln1a (overwritten by kv after Q gemm)
  //   [35,51) kv [16384][512] bf16
  //   [43,51) hb (after attn; kv dead)
  __hip_bfloat16* wbf   = (__hip_bfloat16*)(ws);
  __hip_bfloat16* ln1b  = (__hip_bfloat16*)(ws + 3*MB);
  __hip_bfloat16* attnb = (__hip_bfloat16*)(ws + 3*MB);
  float*          diff  = (float*)(ws + 11*MB);
  __hip_bfloat16* h1h   = (__hip_bfloat16*)(ws + 11*MB);
  __hip_bfloat16* qbuf  = (__hip_bfloat16*)(ws + 27*MB);
  float*          xmid  = (float*)(ws + 27*MB);
  __hip_bfloat16* ln1a  = (__hip_bfloat16*)(ws + 35*MB);
  __hip_bfloat16* kv    = (__hip_bfloat16*)(ws + 35*MB);
  __hip_bfloat16* hb    = (__hip_bfloat16*)(ws + 43*MB);

  convert_k<<<6144, 256, 0, stream>>>(qw, kw, vw, pw, f1w, f2w, wbf);

  for (int bi = 0; bi < 2; ++bi) {
    const short* wq = (const short*)(wbf + (size_t)bi * 786432);
    const short* wkv = wq + 65536;           // kw rows 0-255 then vw rows 256-511
    const short* wp  = wq + 196608;
    const short* w1  = wq + 262144;
    const short* w2  = wq + 524288;
    float av = (bi == 0) ? 1.f : -1.f, ai = (bi == 0) ? -1.f : 1.f;
    float bv = (bi == 0) ? 0.f : 1.f,  bb = (bi == 0) ? 1.f : 0.f;

    prep2_k<<<1024, 256, 0, stream>>>(x, n1w + bi*256, n1b + bi*256, ln1a, ln1b, diff, av, ai, bv, bb);

    gemm3_k<0><<<dim3(128,4), 256, 0, stream>>>((const short*)ln1a, wq,  qbuf, nullptr, nullptr, 256, 256, 0, 0);
    gemm3_k<0><<<dim3(128,8), 256, 0, stream>>>((const short*)ln1b, wkv, kv,   nullptr, nullptr, 256, 512, 0, 0);

    attn2_k<<<512, 256, 0, stream>>>(qbuf, kv, attnb);

    gemm3_k<1><<<dim3(128,4), 256, 0, stream>>>((const short*)attnb, wp, xmid, pb + bi*256, diff, 256, 256, 256, 0);
    ln2_k<<<4096, 256, 0, stream>>>(xmid, n2w + bi*256, n2b + bi*256, hb);

    float* outb = outp + (size_t)bi * 4194304;
    for (int pass = 0; pass < 2; ++pass) {
      const short* hbp = (const short*)hb + (size_t)pass * 8192 * 256;
      const float* xmp = xmid + (size_t)pass * 8192 * 256;
      gemm3_k<2><<<dim3(64,16), 256, 0, stream>>>(hbp, w1, h1h, f1b + bi*1024, nullptr, 256, 1024, 0, 0);
      gemm3_k<3><<<dim3(64,4), 256, 0, stream>>>((const short*)h1h, w2, outb, f2b + bi*256, xmp, 1024, 256, 256, pass * 8192);
    }
  }
}

// Round 5
// 310.114 us; speedup vs baseline: 1.0837x; 1.0837x over previous
//
#include <hip/hip_runtime.h>
#include <hip/hip_bf16.h>

typedef __attribute__((ext_vector_type(8))) short bf16x8;
typedef __attribute__((ext_vector_type(4))) float f32x4;

#define HWSZ 4096
#define NPIX 16384

__device__ inline float b2f(short s) {
  return __uint_as_float(((unsigned)(unsigned short)s) << 16);
}
__device__ inline short f2b(float f) {
  __hip_bfloat16 h = __float2bfloat16(f);
  return *(short*)&h;
}
__device__ inline void gl16(const short* g, short* l) {
  __builtin_amdgcn_global_load_lds(
      (const __attribute__((address_space(1))) unsigned int*)g,
      (__attribute__((address_space(3))) unsigned int*)l, 16, 0, 0);
}
// GELU exact-erf via Abramowitz-Stegun 7.1.26 (|abs err| <= 1.5e-7)
__device__ inline float gelu_f(float x) {
  float ax = fabsf(x) * 0.70710678118654752f;
  float t = 1.f / (1.f + 0.3275911f * ax);
  float y = t * (0.254829592f + t * (-0.284496736f + t * (1.421413741f +
            t * (-1.453152027f + t * 1.061405429f))));
  float erfv = 1.f - y * __expf(-ax * ax);
  erfv = copysignf(erfv, x);
  return 0.5f * x * (1.f + erfv);
}

// ---------------- weight fp32 -> bf16 conversion ----------------
// wbf per bi (elems): qw 0, kw 65536, vw 131072, pw 196608, fc1w 262144, fc2w 524288; total 786432
__global__ __launch_bounds__(256) void convert_k(
    const float* __restrict__ qw, const float* __restrict__ kw,
    const float* __restrict__ vw, const float* __restrict__ pw,
    const float* __restrict__ f1, const float* __restrict__ f2,
    __hip_bfloat16* __restrict__ out)
{
  int idx = blockIdx.x * 256 + threadIdx.x;
  if (idx >= 2 * 786432) return;
  int bi = idx / 786432;
  int r  = idx - bi * 786432;
  float v;
  if      (r <  65536) v = qw[bi*65536 + r];
  else if (r < 131072) v = kw[bi*65536 + r - 65536];
  else if (r < 196608) v = vw[bi*65536 + r - 131072];
  else if (r < 262144) v = pw[bi*65536 + r - 196608];
  else if (r < 524288) v = f1[bi*262144 + r - 262144];
  else                 v = f2[bi*262144 + r - 524288];
  out[idx] = __float2bfloat16(v);
}

// ---------------- fused prep: both LN1 variants + raw diff, BCHW -> (pix, ch) ----------------
__global__ __launch_bounds__(256) void prep2_k(
    const float* __restrict__ x,     // (2,4,256,64,64)
    const float* __restrict__ nw, const float* __restrict__ nb,
    __hip_bfloat16* __restrict__ ln1a,   // LN(av*vi+ai*ir)
    __hip_bfloat16* __restrict__ ln1b,   // LN(bv*vi+bb*ir)
    float* __restrict__ diff,            // av*vi+ai*ir (raw)
    float av, float ai, float bv, float bb)
{
  __shared__ float t1[16][257], t2[16][257];
  __shared__ float red[4][16][16];
  __shared__ float mu1[16], rs1[16], mu2[16], rs2[16];
  int t = threadIdx.x;
  int pix0 = blockIdx.x * 16;
  int b = pix0 >> 12, hw0 = pix0 & 4095;
  const float* vi = x + (size_t)b * 256 * HWSZ;
  const float* ir = x + (size_t)(4 + b) * 256 * HWSZ;

  for (int it = 0; it < 16; ++it) {
    int idx = it * 256 + t;
    int p = idx & 15, c = idx >> 4;
    size_t off = (size_t)c * HWSZ + hw0 + p;
    float a = vi[off], bb2 = ir[off];
    t1[p][c] = av * a + ai * bb2;
    t2[p][c] = bv * a + bb * bb2;
  }
  __syncthreads();
  {
    int p = t & 15, q = t >> 4;
    float s1 = 0, ss1 = 0, s2 = 0, ss2 = 0;
    for (int i = 0; i < 16; ++i) {
      float v = t1[p][q*16 + i]; s1 += v; ss1 += v*v;
      float u = t2[p][q*16 + i]; s2 += u; ss2 += u*u;
    }
    red[0][p][q] = s1; red[1][p][q] = ss1; red[2][p][q] = s2; red[3][p][q] = ss2;
  }
  __syncthreads();
  if (t < 32) {
    int p = t & 15, which = t >> 4;
    float s = 0, ss = 0;
    for (int q = 0; q < 16; ++q) { s += red[which*2][p][q]; ss += red[which*2+1][p][q]; }
    float mu = s * (1.f/256.f);
    float var = ss * (1.f/256.f) - mu*mu;
    float rs = rsqrtf(var + 1e-5f);
    if (which == 0) { mu1[p] = mu; rs1[p] = rs; }
    else            { mu2[p] = mu; rs2[p] = rs; }
  }
  __syncthreads();
  for (int it = 0; it < 16; ++it) {
    float v1 = t1[it][t], v2 = t2[it][t];
    size_t o = (size_t)(pix0 + it) * 256 + t;
    ln1a[o] = __float2bfloat16((v1 - mu1[it]) * rs1[it] * nw[t] + nb[t]);
    ln1b[o] = __float2bfloat16((v2 - mu2[it]) * rs2[it] * nw[t] + nb[t]);
    diff[o] = v1;
  }
}

// ---------------- A-stationary MFMA GEMM (K=256): C[M x N] = A * W^T ----------------
// Block 128(M) x 64(N); 4 waves 2x2; wave tile 64x32.
// EPI 0: bf16 out[row*ldc+col]; EPI 1: fp32 out = acc + bias[col] + res[row*Nres+col]
template<int EPI>
__global__ __launch_bounds__(256) void gemm3_k(
    const short* __restrict__ A, const short* __restrict__ W,
    void* __restrict__ outp, const float* __restrict__ bias,
    const float* __restrict__ res,
    int K, int ldc, int Nres, int row_base)
{
  __shared__ __align__(16) short As[128 * 256];   // 64 KB
  int tid = threadIdx.x;
  int l = tid & 63, wv = tid >> 6;
  int wm = wv >> 1, wn = wv & 1;
  int m0 = blockIdx.x * 128;
  int n0 = blockIdx.y * 64;
  int lr = l & 15, lq = l >> 4;

  f32x4 acc[4][2];
  #pragma unroll
  for (int mi = 0; mi < 4; ++mi)
    #pragma unroll
    for (int ni = 0; ni < 2; ++ni) acc[mi][ni] = (f32x4){0.f, 0.f, 0.f, 0.f};

  const short* pB = W + (size_t)(n0 + wn * 32 + lr) * K + lq * 8;

  for (int kb = 0; kb < K; kb += 256) {
    bf16x8 bfall[8][2];
    #pragma unroll
    for (int ks = 0; ks < 8; ++ks)
      #pragma unroll
      for (int ni = 0; ni < 2; ++ni)
        bfall[ks][ni] = *(const bf16x8*)(pB + (size_t)ni * 16 * K + kb + ks * 32);

    #pragma unroll
    for (int i = 0; i < 16; ++i) {
      int idx = i * 256 + tid;
      int row = idx >> 5, c = idx & 31;
      const short* g = A + (size_t)(m0 + row) * K + kb + ((c ^ (row & 7)) << 3);
      gl16(g, As + idx * 8);
    }
    __syncthreads();

    #pragma unroll
    for (int ks = 0; ks < 8; ++ks) {
      int kc0 = ks * 4 + lq;
      bf16x8 af[4];
      #pragma unroll
      for (int mi = 0; mi < 4; ++mi) {
        int row = wm * 64 + mi * 16 + lr;
        int kc = kc0 ^ (row & 7);
        af[mi] = *(const bf16x8*)(As + row * 256 + kc * 8);
      }
      #pragma unroll
      for (int mi = 0; mi < 4; ++mi)
        #pragma unroll
        for (int ni = 0; ni < 2; ++ni)
          acc[mi][ni] = __builtin_amdgcn_mfma_f32_16x16x32_bf16(af[mi], bfall[ks][ni], acc[mi][ni], 0, 0, 0);
    }
    __syncthreads();
  }

  #pragma unroll
  for (int mi = 0; mi < 4; ++mi)
  #pragma unroll
  for (int ni = 0; ni < 2; ++ni) {
    #pragma unroll
    for (int r = 0; r < 4; ++r) {
      int row = m0 + wm * 64 + mi * 16 + lq * 4 + r;
      int col = n0 + wn * 32 + ni * 16 + lr;
      float v = acc[mi][ni][r];
      if (EPI == 0) {
        ((__hip_bfloat16*)outp)[(size_t)row * ldc + col] = __float2bfloat16(v);
      } else {
        v += bias[col] + res[(size_t)row * Nres + col];
        ((float*)outp)[(size_t)row * ldc + col] = v;
      }
    }
  }
}

// ---------------- fused FFN: out = x + fc2(gelu(fc1(h))) , BCHW fp32 direct ----------------
// Block = 64 rows, 4 waves, 256 thr. A (64x256) staged once in LDS (chunk-swizzled).
// Loop 8 chunks of 128 fc1-cols: fc1-MFMA (W1 global->reg) -> gelu -> Hs (XOR-swizzled LDS)
// -> fc2-MFMA accumulating acc2. Weights L2-resident; h never leaves the CU.
__global__ __launch_bounds__(256) void ffn_k(
    const short* __restrict__ A,      // hb  [16384][256] bf16
    const short* __restrict__ W1,     // [1024][256] bf16
    const float* __restrict__ B1,     // [1024]
    const short* __restrict__ W2,     // [256][1024] bf16
    const float* __restrict__ B2,     // [256]
    const float* __restrict__ res,    // xmid [16384][256] fp32
    float* __restrict__ outp)         // BCHW fp32 (4,256,64,64) for this bi
{
  __shared__ __align__(16) short As[64 * 256];   // 32 KB
  __shared__ __align__(16) short Hs[64 * 128];   // 16 KB
  int tid = threadIdx.x;
  int l = tid & 63, w = tid >> 6;
  int lr = l & 15, lq = l >> 4;
  int m0 = blockIdx.x * 64;

  // stage A rows m0..m0+64, source-side chunk swizzle c^=(row&7) on 16B chunks
  #pragma unroll
  for (int i = 0; i < 8; ++i) {
    int idx = i * 256 + tid;
    int row = idx >> 5, c = idx & 31;
    gl16(A + (size_t)(m0 + row) * 256 + ((c ^ (row & 7)) << 3), As + idx * 8);
  }

  f32x4 acc2[4][4];
  #pragma unroll
  for (int mi = 0; mi < 4; ++mi)
    #pragma unroll
    for (int ni = 0; ni < 4; ++ni) acc2[mi][ni] = (f32x4){0.f, 0.f, 0.f, 0.f};

  __syncthreads();

  for (int ch = 0; ch < 8; ++ch) {
    // ---- fc1: h[64 x 128-chunk]; this wave: all 64 rows x cols [w*32, w*32+32)
    f32x4 acc1[4][2];
    #pragma unroll
    for (int mi = 0; mi < 4; ++mi)
      #pragma unroll
      for (int ni = 0; ni < 2; ++ni) acc1[mi][ni] = (f32x4){0.f, 0.f, 0.f, 0.f};

    #pragma unroll
    for (int kk = 0; kk < 8; ++kk) {
      bf16x8 w1f[2];
      #pragma unroll
      for (int ni = 0; ni < 2; ++ni)
        w1f[ni] = *(const bf16x8*)(W1 + (size_t)(ch * 128 + w * 32 + ni * 16 + lr) * 256 + kk * 32 + lq * 8);
      #pragma unroll
      for (int mi = 0; mi < 4; ++mi) {
        int row = mi * 16 + lr;
        int kc = (kk * 4 + lq) ^ (row & 7);
        bf16x8 af = *(const bf16x8*)(As + row * 256 + kc * 8);
        #pragma unroll
        for (int ni = 0; ni < 2; ++ni)
          acc1[mi][ni] = __builtin_amdgcn_mfma_f32_16x16x32_bf16(af, w1f[ni], acc1[mi][ni], 0, 0, 0);
      }
    }

    // ---- gelu + write h-chunk to Hs with byte-XOR swizzle ((row>>2)&3)<<5
    float b1v[2];
    #pragma unroll
    for (int ni = 0; ni < 2; ++ni) b1v[ni] = B1[ch * 128 + w * 32 + ni * 16 + lr];
    #pragma unroll
    for (int mi = 0; mi < 4; ++mi)
      #pragma unroll
      for (int ni = 0; ni < 2; ++ni)
        #pragma unroll
        for (int r = 0; r < 4; ++r) {
          int row = mi * 16 + lq * 4 + r;
          int col = w * 32 + ni * 16 + lr;
          float v = gelu_f(acc1[mi][ni][r] + b1v[ni]);
          *(short*)((char*)Hs + row * 256 + ((col * 2) ^ (((row >> 2) & 3) << 5))) = f2b(v);
        }
    __syncthreads();

    // ---- fc2: acc2 += h_chunk @ W2[:, chunk]^T ; this wave: 64 rows x cols [w*64, w*64+64)
    #pragma unroll
    for (int kk = 0; kk < 4; ++kk) {
      bf16x8 w2f[4];
      #pragma unroll
      for (int ni = 0; ni < 4; ++ni)
        w2f[ni] = *(const bf16x8*)(W2 + (size_t)(w * 64 + ni * 16 + lr) * 1024 + ch * 128 + kk * 32 + lq * 8);
      #pragma unroll
      for (int mi = 0; mi < 4; ++mi) {
        int row = mi * 16 + lr;
        bf16x8 hf = *(const bf16x8*)((char*)Hs + row * 256 + ((kk * 64 + lq * 16) ^ (((row >> 2) & 3) << 5)));
        #pragma unroll
        for (int ni = 0; ni < 4; ++ni)
          acc2[mi][ni] = __builtin_amdgcn_mfma_f32_16x16x32_bf16(hf, w2f[ni], acc2[mi][ni], 0, 0, 0);
      }
    }
    __syncthreads();   // Hs consumed; next chunk may overwrite
  }

  // ---- epilogue: + b2 + residual, scatter to BCHW fp32 (L2 merges lines)
  #pragma unroll
  for (int mi = 0; mi < 4; ++mi)
  #pragma unroll
  for (int ni = 0; ni < 4; ++ni) {
    #pragma unroll
    for (int r = 0; r < 4; ++r) {
      int grow = m0 + mi * 16 + lq * 4 + r;
      int col = w * 64 + ni * 16 + lr;
      float v = acc2[mi][ni][r] + B2[col] + res[(size_t)grow * 256 + col];
      int b = grow >> 12, hw = grow & 4095;
      outp[(size_t)(b * 256 + col) * HWSZ + hw] = v;
    }
  }
}

// ---------------- dilated local attention: one thread per (pixel, head) ----------------
__global__ __launch_bounds__(256) void attn2_k(
    const __hip_bfloat16* __restrict__ Q,
    const __hip_bfloat16* __restrict__ KV,
    __hip_bfloat16* __restrict__ out)
{
  int gid = blockIdx.x * 256 + threadIdx.x;
  int pix = gid >> 3, head = gid & 7;
  int dil = (head >> 1) + 1;
  int y = (pix >> 6) & 63, xc = pix & 63;
  int base = pix & ~4095;
  const short* q8 = (const short*)Q + (size_t)pix * 256 + head * 32;
  float qf[32];
  #pragma unroll
  for (int j = 0; j < 4; ++j) {
    bf16x8 v = *(const bf16x8*)(q8 + j * 8);
    #pragma unroll
    for (int e = 0; e < 8; ++e) qf[j*8 + e] = b2f(v[e]);
  }
  float lg[9];
  int npx[9];
  #pragma unroll
  for (int t = 0; t < 9; ++t) {
    int ny = y + (t / 3 - 1) * dil;
    int nx = xc + (t % 3 - 1) * dil;
    bool ok = ((unsigned)ny < 64u) && ((unsigned)nx < 64u);
    npx[t] = ok ? (base | (ny * 64 + nx)) : -1;
    float d = 0.f;
    if (ok) {
      const short* k8 = (const short*)KV + (size_t)npx[t] * 512 + head * 32;
      #pragma unroll
      for (int j = 0; j < 4; ++j) {
        bf16x8 v = *(const bf16x8*)(k8 + j * 8);
        #pragma unroll
        for (int e = 0; e < 8; ++e) d += qf[j*8 + e] * b2f(v[e]);
      }
    }
    lg[t] = d * 0.17677669529663687f;   // 32^-0.5
  }
  float m = lg[0];
  #pragma unroll
  for (int t = 1; t < 9; ++t) m = fmaxf(m, lg[t]);
  float w[9], den = 0.f;
  #pragma unroll
  for (int t = 0; t < 9; ++t) { w[t] = expf(lg[t] - m); den += w[t]; }
  float inv = 1.f / den;
  float acc[32];
  #pragma unroll
  for (int j = 0; j < 32; ++j) acc[j] = 0.f;
  #pragma unroll
  for (int t = 0; t < 9; ++t) {
    if (npx[t] >= 0) {
      const short* v8 = (const short*)KV + (size_t)npx[t] * 512 + 256 + head * 32;
      float wt = w[t];
      #pragma unroll
      for (int j = 0; j < 4; ++j) {
        bf16x8 v = *(const bf16x8*)(v8 + j * 8);
        #pragma unroll
        for (int e = 0; e < 8; ++e) acc[j*8 + e] += wt * b2f(v[e]);
      }
    }
  }
  short* op = (short*)out + (size_t)pix * 256 + head * 32;
  #pragma unroll
  for (int j = 0; j < 4; ++j) {
    bf16x8 o;
    #pragma unroll
    for (int e = 0; e < 8; ++e) o[e] = f2b(acc[j*8 + e] * inv);
    *(bf16x8*)(op + j * 8) = o;
  }
}

// ---------------- LN2: fp32 (pix,ch) -> bf16 (pix,ch) ----------------
__global__ __launch_bounds__(256) void ln2_k(
    const float* __restrict__ xm, const float* __restrict__ w2,
    const float* __restrict__ b2, __hip_bfloat16* __restrict__ h)
{
  int pix = blockIdx.x * 4 + (threadIdx.x >> 6);
  int l = threadIdx.x & 63;
  const float4 v = *(const float4*)(xm + (size_t)pix * 256 + l * 4);
  float s  = v.x + v.y + v.z + v.w;
  float ss = v.x*v.x + v.y*v.y + v.z*v.z + v.w*v.w;
  #pragma unroll
  for (int off = 32; off; off >>= 1) { s += __shfl_xor(s, off); ss += __shfl_xor(ss, off); }
  float mu = s * (1.f/256.f);
  float rstd = rsqrtf(ss * (1.f/256.f) - mu*mu + 1e-5f);
  float vv[4] = {v.x, v.y, v.z, v.w};
  #pragma unroll
  for (int j = 0; j < 4; ++j) {
    int c = l * 4 + j;
    h[(size_t)pix * 256 + c] = __float2bfloat16((vv[j] - mu) * rstd * w2[c] + b2[c]);
  }
}

extern "C" void kernel_launch(void* const* d_in, const int* in_sizes, int n_in,
                              void* d_out, int out_size, void* d_ws, size_t ws_size,
                              hipStream_t stream)
{
  const float* x   = (const float*)d_in[0];
  const float* n1w = (const float*)d_in[1];
  const float* n1b = (const float*)d_in[2];
  const float* qw  = (const float*)d_in[3];
  const float* kw  = (const float*)d_in[4];
  const float* vw  = (const float*)d_in[5];
  const float* pw  = (const float*)d_in[6];
  const float* pb  = (const float*)d_in[7];
  const float* n2w = (const float*)d_in[8];
  const float* n2b = (const float*)d_in[9];
  const float* f1w = (const float*)d_in[10];
  const float* f1b = (const float*)d_in[11];
  const float* f2w = (const float*)d_in[12];
  const float* f2b = (const float*)d_in[13];
  float* outp = (float*)d_out;
  char* ws = (char*)d_ws;

  const size_t MB = 1024 * 1024;
  // Workspace high-water 51 MB (proven safe). Lifetimes per bi:
  //   [0,3)   wbf (whole session)
  //   [3,11)  ln1b -> attnb
  //   [11,27) diff fp32 (residual for proj)
  //   [27,43) qbuf (27-35) -> xmid fp32 (27-43)
  //   [35,51) ln1a (35-43) -> kv (35-51) -> hb (43-51, kv dead after attn)
  __hip_bfloat16* wbf   = (__hip_bfloat16*)(ws);
  __hip_bfloat16* ln1b  = (__hip_bfloat16*)(ws + 3*MB);
  __hip_bfloat16* attnb = (__hip_bfloat16*)(ws + 3*MB);
  float*          diff  = (float*)(ws + 11*MB);
  __hip_bfloat16* qbuf  = (__hip_bfloat16*)(ws + 27*MB);
  float*          xmid  = (float*)(ws + 27*MB);
  __hip_bfloat16* ln1a  = (__hip_bfloat16*)(ws + 35*MB);
  __hip_bfloat16* kv    = (__hip_bfloat16*)(ws + 35*MB);
  __hip_bfloat16* hb    = (__hip_bfloat16*)(ws + 43*MB);

  convert_k<<<6144, 256, 0, stream>>>(qw, kw, vw, pw, f1w, f2w, wbf);

  for (int bi = 0; bi < 2; ++bi) {
    const short* wq  = (const short*)(wbf + (size_t)bi * 786432);
    const short* wkv = wq + 65536;           // kw rows then vw rows (512 x 256)
    const short* wp  = wq + 196608;
    const short* w1  = wq + 262144;
    const short* w2  = wq + 524288;
    float av = (bi == 0) ? 1.f : -1.f, ai = (bi == 0) ? -1.f : 1.f;
    float bv = (bi == 0) ? 0.f : 1.f,  bb = (bi == 0) ? 1.f : 0.f;

    prep2_k<<<1024, 256, 0, stream>>>(x, n1w + bi*256, n1b + bi*256, ln1a, ln1b, diff, av, ai, bv, bb);

    gemm3_k<0><<<dim3(128,4), 256, 0, stream>>>((const short*)ln1a, wq,  qbuf, nullptr, nullptr, 256, 256, 0, 0);
    gemm3_k<0><<<dim3(128,8), 256, 0, stream>>>((const short*)ln1b, wkv, kv,   nullptr, nullptr, 256, 512, 0, 0);

    attn2_k<<<512, 256, 0, stream>>>(qbuf, kv, attnb);

    gemm3_k<1><<<dim3(128,4), 256, 0, stream>>>((const short*)attnb, wp, xmid, pb + bi*256, diff, 256, 256, 256, 0);
    ln2_k<<<4096, 256, 0, stream>>>(xmid, n2w + bi*256, n2b + bi*256, hb);

    ffn_k<<<256, 256, 0, stream>>>((const short*)hb, w1, f1b + bi*1024, w2, f2b + bi*256,
                                   xmid, outp + (size_t)bi * 4194304);
  }
}